// Round 1
// 293.803 us; speedup vs baseline: 1.2294x; 1.2294x over previous
//
#include <hip/hip_runtime.h>
#include <hip/hip_bf16.h>
#include <cstdint>
#include <cstddef>

#define V_TEXT   256
#define V_TOTAL  4352
#define V_AUDIO  4096
#define B_       8
#define H_       4
#define TQ_      800
#define TK_      128
#define T_TOK    1024
#define NSEQ     32
#define K2       1.4426950408889634f   // 1/ln2
#define LN2      0.6931471805599453f
#define EB8      11.541560327111707f   // 8*K2  (blank log2-prob magnitude)
#define EM8      3.3546262790251185e-04f // e^-8 = 2^-EB8 (linear blank emission)
#define FNEGINF  (-3.0e38f)
#define CHK      60                    // timesteps per LDS chunk
#define NCH      14                    // ceil(800/60)

// ---- DPP helpers (ctrl must be a compile-time constant) ----
template <int CTRL>
__device__ __forceinline__ float dpp_mov(float x, float old) {
    return __int_as_float(__builtin_amdgcn_update_dpp(
        __float_as_int(old), __float_as_int(x), CTRL, 0xf, 0xf, false));
}
__device__ __forceinline__ float dpp_shr1_old(float x, float old) {
    return dpp_mov<0x138>(x, old);      // wave_shr:1
}
__device__ __forceinline__ float lane_bcast(float x, int lane) {
    return __int_as_float(__builtin_amdgcn_readlane(__float_as_int(x), lane));
}
__device__ __forceinline__ float wave_max(float x) {
    x = fmaxf(x, dpp_mov<0x111>(x, FNEGINF));
    x = fmaxf(x, dpp_mov<0x112>(x, FNEGINF));
    x = fmaxf(x, dpp_mov<0x114>(x, FNEGINF));
    x = fmaxf(x, dpp_mov<0x118>(x, FNEGINF));
    x = fmaxf(x, dpp_mov<0x142>(x, FNEGINF));
    x = fmaxf(x, dpp_mov<0x143>(x, FNEGINF));
    return lane_bcast(x, 63);
}
__device__ __forceinline__ float wave_sum(float x) {
    x += dpp_mov<0x111>(x, 0.0f);
    x += dpp_mov<0x112>(x, 0.0f);
    x += dpp_mov<0x114>(x, 0.0f);
    x += dpp_mov<0x118>(x, 0.0f);
    x += dpp_mov<0x142>(x, 0.0f);
    x += dpp_mov<0x143>(x, 0.0f);
    return lane_bcast(x, 63);
}

// ---------- Kernel 1: per-row CE nll, one wave per row ----------
__global__ __launch_bounds__(256) void ce_kernel(
    const float* __restrict__ logits, const int* __restrict__ targets,
    const int* __restrict__ alens, float* __restrict__ nll_out)
{
    int w = threadIdx.x >> 6, lane = threadIdx.x & 63;
    int row = blockIdx.x * 4 + w;
    const float* p = logits + (size_t)row * V_TOTAL + V_TEXT;

    float4 v0 = *reinterpret_cast<const float4*>(p + lane * 4);
    float4 v1 = *reinterpret_cast<const float4*>(p + lane * 4 + 1024);
    float4 v2 = *reinterpret_cast<const float4*>(p + lane * 4 + 2048);
    float4 v3 = *reinterpret_cast<const float4*>(p + lane * 4 + 3072);
    int tg = targets[row];

    float m = fmaxf(fmaxf(fmaxf(v0.x, v0.y), fmaxf(v0.z, v0.w)),
                    fmaxf(fmaxf(v1.x, v1.y), fmaxf(v1.z, v1.w)));
    m = fmaxf(m, fmaxf(fmaxf(v2.x, v2.y), fmaxf(v2.z, v2.w)));
    m = fmaxf(m, fmaxf(fmaxf(v3.x, v3.y), fmaxf(v3.z, v3.w)));
    m = wave_max(m);

    float mn = -m * K2;
    float s =
      __builtin_exp2f(__builtin_fmaf(v0.x,K2,mn)) + __builtin_exp2f(__builtin_fmaf(v0.y,K2,mn))
    + __builtin_exp2f(__builtin_fmaf(v0.z,K2,mn)) + __builtin_exp2f(__builtin_fmaf(v0.w,K2,mn))
    + __builtin_exp2f(__builtin_fmaf(v1.x,K2,mn)) + __builtin_exp2f(__builtin_fmaf(v1.y,K2,mn))
    + __builtin_exp2f(__builtin_fmaf(v1.z,K2,mn)) + __builtin_exp2f(__builtin_fmaf(v1.w,K2,mn))
    + __builtin_exp2f(__builtin_fmaf(v2.x,K2,mn)) + __builtin_exp2f(__builtin_fmaf(v2.y,K2,mn))
    + __builtin_exp2f(__builtin_fmaf(v2.z,K2,mn)) + __builtin_exp2f(__builtin_fmaf(v2.w,K2,mn))
    + __builtin_exp2f(__builtin_fmaf(v3.x,K2,mn)) + __builtin_exp2f(__builtin_fmaf(v3.y,K2,mn))
    + __builtin_exp2f(__builtin_fmaf(v3.z,K2,mn)) + __builtin_exp2f(__builtin_fmaf(v3.w,K2,mn));
    s = wave_sum(s);

    if (lane == 0) {
        float lse = m + __builtin_log2f(s) * LN2;
        int b = row >> 10, t = row & (T_TOK - 1);
        bool valid = (t < alens[b]) && (tg != -100);
        float nll = 0.0f;
        if (valid) {
            int idx = min(max(tg - V_TEXT, 0), V_AUDIO - 1);
            nll = lse - p[idx];
        }
        nll_out[row] = nll;
    }
}

// ---------- producer helper: stage one 60-row chunk as LINEAR emissions ----
// Writes e = 2^{x*K2} (masked to 0 for cols >= k) into db, and accumulates
// the per-row softmax denominator  prod *= (sum_j e_j + e^-8)  as a
// mantissa-product with integer exponent accumulation (no per-row log2).
__device__ __forceinline__ void stage_rows(
    float* db, const float* __restrict__ abase, int g0, int k, int q,
    int lane, float& prod, int& acc)
{
    int half = lane >> 5, col = (lane & 31) * 4;
    #pragma unroll 6
    for (int i = 0; i < CHK / 2; i++) {
        int r  = 2 * i + half;
        int rg = g0 + r;
        int rc = min(rg, TQ_ - 1);      // clamp: no OOB past attn
        float4 v = *reinterpret_cast<const float4*>(abase + (size_t)rc * TK_ + col);
        float e0 = (col + 0 < k) ? __builtin_exp2f(v.x * K2) : 0.0f;
        float e1 = (col + 1 < k) ? __builtin_exp2f(v.y * K2) : 0.0f;
        float e2 = (col + 2 < k) ? __builtin_exp2f(v.z * K2) : 0.0f;
        float e3 = (col + 3 < k) ? __builtin_exp2f(v.w * K2) : 0.0f;
        *reinterpret_cast<float4*>(db + r * TK_ + col) = make_float4(e0, e1, e2, e3);

        // row denominator: butterfly over the 32 lanes of this row-half
        float ps = (e0 + e1) + (e2 + e3);
        ps += __shfl_xor(ps, 1);
        ps += __shfl_xor(ps, 2);
        ps += __shfl_xor(ps, 4);
        ps += __shfl_xor(ps, 8);
        ps += __shfl_xor(ps, 16);
        ps += EM8;                       // + blank term 2^-EB8
        prod *= (rg < q) ? ps : 1.0f;
        if ((i % 3) == 2) {              // renorm every 3 multiplies (exact)
            int b = __float_as_int(prod);
            acc += (b >> 23) - 127;
            prod = __int_as_float((b & 0x007fffff) | 0x3f800000);
        }
    }
}

// ---------- Kernel 2: CTC recursion in SCALED LINEAR domain ----------
// Chain per step is add->add->mul (+DPP shift): no transcendentals on the
// critical path. exp2 of emissions is done by the producer wave (off-chain).
// Exact power-of-2 rescale every 8 steps keeps values in float range; the
// stripped exponents accumulate in Mtot. Softmax normalizer (old lse_kernel)
// is folded into the producer (Csum), so that kernel is gone.
__global__ __launch_bounds__(128) void rec_kernel(
    const float* __restrict__ attn,
    const int* __restrict__ src_lens, const int* __restrict__ out_lens,
    float* __restrict__ loss_out)
{
    __shared__ float buf[2][CHK][TK_];   // 61440 B (linear emissions)
    __shared__ float csh;                // producer -> consumer: Csum (log2)
    int n   = blockIdx.x;
    int tid = threadIdx.x;
    int wid = tid >> 6, lane = tid & 63;
    int k = min(src_lens[n >> 2], TK_);
    int q = min(out_lens[n >> 2], TQ_);
    int ncha = (q + CHK - 1) / CHK;
    const float* abase = attn + (size_t)n * TQ_ * TK_;

    // producer-side normalizer accumulators
    float prod = 1.0f;
    int   acc  = 0;

    // consumer state: lane l holds states 4l..4l+3 (p0..p3); p4 = state 256
    // (valid on lane 63). Virtual pre-state: p0=1 on lane 0 makes t=0 a
    // regular step, so every chunk runs uniformly.
    float p0 = (wid == 0 && lane == 0) ? 1.0f : 0.0f;
    float p1 = 0.0f, p2 = 0.0f, p3 = 0.0f, p4 = 0.0f, p3s = 0.0f;
    int   Mtot = 0;      // sum of stripped log2 scales
    int   rsc  = 0;      // rescale cadence counter (every 2 groups = 8 steps)

    if (wid == 1) stage_rows(&buf[0][0][0], abase, 0, k, q, lane, prod, acc);
    __syncthreads();

#define SSTEP(xv)                                                            \
    do {                                                                     \
        float c01 = p0 + p3s;          /* states s, s-1           */         \
        float c12 = p2 + p1;                                                 \
        float n4  = (p4 + p3) * EM8;   /* state 256 (blank)       */         \
        p0 = c01 * EM8;                /* even: blank emission    */         \
        p1 = (p1 + c01) * xv.x;        /* odd: 3-way + label col 2l   */     \
        p2 = c12 * EM8;                                                      \
        p3 = (p3 + c12) * xv.y;        /* odd: 3-way + label col 2l+1 */     \
        p4 = n4;                                                             \
        p3s = dpp_shr1_old(p3, 0.0f);  /* shift state 4l+3 -> lane l+1 */    \
    } while (0)

#define RESCALE()                                                            \
    do {                                                                     \
        float wm = fmaxf(fmaxf(fmaxf(p0, p1), fmaxf(p2, p3)),                \
                         fmaxf(p4, p3s));                                    \
        wm = wave_max(wm);                                                   \
        int ebits = __float_as_int(wm) & 0x7f800000;                         \
        if (ebits > 0) {               /* skip if all-zero/denormal */       \
            int se = 294 - (ebits >> 23);  /* park max at 2^40 */            \
            se = se < 1 ? 1 : (se > 254 ? 254 : se);                         \
            float sc = __int_as_float(se << 23);                             \
            Mtot += 127 - se;                                                \
            p0 *= sc; p1 *= sc; p2 *= sc; p3 *= sc; p4 *= sc; p3s *= sc;     \
        }                                                                    \
    } while (0)

    for (int c = 0; c < ncha; c++) {
        if (wid == 1) {
            if (c + 1 < ncha)
                stage_rows(&buf[(c + 1) & 1][0][0], abase, (c + 1) * CHK,
                           k, q, lane, prod, acc);
        } else {
            const float* lb = &buf[c & 1][0][2 * lane];
            int lim = min(CHK, q - c * CHK);
            int ts = 0;
            if (ts < lim) {
#define LD(j) (*reinterpret_cast<const float2*>(lb + min((j), CHK - 1) * TK_))
                float2 A = LD(0), Bv = LD(1), Cv = LD(2), Dv = LD(3);
                for (; ts + 4 <= lim; ts += 4) {
                    float2 nA = LD(ts + 4), nB = LD(ts + 5),
                           nC = LD(ts + 6), nD = LD(ts + 7);
                    SSTEP(A); SSTEP(Bv); SSTEP(Cv); SSTEP(Dv);
                    if (++rsc == 2) { rsc = 0; RESCALE(); }
                    A = nA; Bv = nB; Cv = nC; Dv = nD;
                }
                for (; ts < lim; ts++) { SSTEP(A); A = Bv; Bv = Cv; Cv = Dv; }
#undef LD
            }
        }
        __syncthreads();
    }
#undef SSTEP
#undef RESCALE

    if (wid == 1) {
        // Csum = sum_t log2(row denominator); each row duplicated 32x -> /32
        float cl = __builtin_log2f(prod) + (float)acc;
        cl = wave_sum(cl) * (1.0f / 32.0f);
        if (lane == 0) csh = cl;
    }
    __syncthreads();

    if (wid == 0) {
        int s1 = 2 * k - 1, s2 = 2 * k;
        float e1v, e2v;
        {
            int l = s1 >> 2, r = s1 & 3;
            float c1 = __shfl(p1, l), c3 = __shfl(p3, l);
            e1v = (r == 1) ? c1 : c3;
        }
        if (s2 == 256) {
            e2v = __shfl(p4, 63);
        } else {
            int l = s2 >> 2, r = s2 & 3;
            float c0 = __shfl(p0, l), c2 = __shfl(p2, l);
            e2v = (r == 0) ? c0 : c2;
        }
        // log2 alpha_norm = log2(p) + Mtot - Csum
        float l2 = __builtin_log2f(e1v + e2v) + (float)Mtot - csh;
        float nll = -l2 * LN2;
        float loss = nll / (float)k;
        if (!(isfinite(loss) && loss < 1.0e8f)) loss = 0.0f;
        if (lane == 0) loss_out[n] = loss;
    }
}

// ---------- Kernel 3: finalize ----------
__global__ __launch_bounds__(256) void fin_kernel(
    const float* __restrict__ nll, const int* __restrict__ alens,
    const int* __restrict__ step, const float* __restrict__ attn_losses,
    float* __restrict__ out)
{
    __shared__ float red[4];
    int tid = threadIdx.x;
    float s = 0.0f;
    for (int i = tid; i < B_ * T_TOK; i += 256) s += nll[i];
    #pragma unroll
    for (int off = 32; off > 0; off >>= 1) s += __shfl_xor(s, off);
    if ((tid & 63) == 0) red[tid >> 6] = s;
    __syncthreads();
    if (tid == 0) {
        float ce_sum = red[0] + red[1] + red[2] + red[3];
        int denom = 0;
        for (int b = 0; b < B_; b++) denom += min(alens[b], T_TOK);
        denom = max(denom, 1);
        float token = ce_sum / (float)denom;
        float a = 0.0f;
        for (int i = 0; i < NSEQ; i++) a += attn_losses[i];
        a *= (1.0f / NSEQ);
        if (step[0] <= 5000) a = 0.0f;
        out[0] = 1.5f * token + 10.0f * a;
        out[1] = a;
        out[2] = token;
    }
}

extern "C" void kernel_launch(void* const* d_in, const int* in_sizes, int n_in,
                              void* d_out, int out_size, void* d_ws, size_t ws_size,
                              hipStream_t stream)
{
    const float* logits  = (const float*)d_in[0];
    const float* attn    = (const float*)d_in[1];
    const int*   targets = (const int*)d_in[2];
    const int*   alens   = (const int*)d_in[3];
    const int*   slens   = (const int*)d_in[4];
    const int*   olens   = (const int*)d_in[5];
    const int*   step    = (const int*)d_in[6];
    float* out = (float*)d_out;
    float* ws  = (float*)d_ws;

    float* ws_attn = ws;            // [0..31]
    float* ws_nll  = ws + 64;       // [64 .. 64+8192)

    ce_kernel <<<dim3(B_ * T_TOK / 4), dim3(256), 0, stream>>>(logits, targets, alens, ws_nll);
    rec_kernel<<<dim3(NSEQ),           dim3(128), 0, stream>>>(attn, slens, olens, ws_attn);
    fin_kernel<<<dim3(1),              dim3(256), 0, stream>>>(ws_nll, alens, step, ws_attn, out);
}

// Round 2
// 281.374 us; speedup vs baseline: 1.2838x; 1.0442x over previous
//
#include <hip/hip_runtime.h>
#include <hip/hip_bf16.h>
#include <cstdint>
#include <cstddef>

#define V_TEXT   256
#define V_TOTAL  4352
#define V_AUDIO  4096
#define B_       8
#define H_       4
#define TQ_      800
#define TK_      128
#define T_TOK    1024
#define NSEQ     32
#define K2       1.4426950408889634f   // 1/ln2
#define LN2      0.6931471805599453f
#define EB8      11.541560327111707f   // 8*K2  (blank log2-prob magnitude)
#define EM8      3.3546262790251185e-04f // e^-8 = 2^-EB8 (linear blank emission)
#define FNEGINF  (-3.0e38f)
#define CHK      60                    // timesteps per LDS chunk
#define NCH      14                    // ceil(800/60)

// ---- DPP helpers (ctrl must be a compile-time constant) ----
template <int CTRL>
__device__ __forceinline__ float dpp_mov(float x, float old) {
    return __int_as_float(__builtin_amdgcn_update_dpp(
        __float_as_int(old), __float_as_int(x), CTRL, 0xf, 0xf, false));
}
__device__ __forceinline__ float dpp_shr1_old(float x, float old) {
    return dpp_mov<0x138>(x, old);      // wave_shr:1
}
__device__ __forceinline__ float lane_bcast(float x, int lane) {
    return __int_as_float(__builtin_amdgcn_readlane(__float_as_int(x), lane));
}
__device__ __forceinline__ float wave_max(float x) {
    x = fmaxf(x, dpp_mov<0x111>(x, FNEGINF));
    x = fmaxf(x, dpp_mov<0x112>(x, FNEGINF));
    x = fmaxf(x, dpp_mov<0x114>(x, FNEGINF));
    x = fmaxf(x, dpp_mov<0x118>(x, FNEGINF));
    x = fmaxf(x, dpp_mov<0x142>(x, FNEGINF));
    x = fmaxf(x, dpp_mov<0x143>(x, FNEGINF));
    return lane_bcast(x, 63);
}
__device__ __forceinline__ float wave_sum(float x) {
    x += dpp_mov<0x111>(x, 0.0f);
    x += dpp_mov<0x112>(x, 0.0f);
    x += dpp_mov<0x114>(x, 0.0f);
    x += dpp_mov<0x118>(x, 0.0f);
    x += dpp_mov<0x142>(x, 0.0f);
    x += dpp_mov<0x143>(x, 0.0f);
    return lane_bcast(x, 63);
}

// ---------- Kernel 1: per-row CE nll, one wave per row ----------
__global__ __launch_bounds__(256) void ce_kernel(
    const float* __restrict__ logits, const int* __restrict__ targets,
    const int* __restrict__ alens, float* __restrict__ nll_out)
{
    int w = threadIdx.x >> 6, lane = threadIdx.x & 63;
    int row = blockIdx.x * 4 + w;
    const float* p = logits + (size_t)row * V_TOTAL + V_TEXT;

    float4 v0 = *reinterpret_cast<const float4*>(p + lane * 4);
    float4 v1 = *reinterpret_cast<const float4*>(p + lane * 4 + 1024);
    float4 v2 = *reinterpret_cast<const float4*>(p + lane * 4 + 2048);
    float4 v3 = *reinterpret_cast<const float4*>(p + lane * 4 + 3072);
    int tg = targets[row];

    float m = fmaxf(fmaxf(fmaxf(v0.x, v0.y), fmaxf(v0.z, v0.w)),
                    fmaxf(fmaxf(v1.x, v1.y), fmaxf(v1.z, v1.w)));
    m = fmaxf(m, fmaxf(fmaxf(v2.x, v2.y), fmaxf(v2.z, v2.w)));
    m = fmaxf(m, fmaxf(fmaxf(v3.x, v3.y), fmaxf(v3.z, v3.w)));
    m = wave_max(m);

    float mn = -m * K2;
    float s =
      __builtin_exp2f(__builtin_fmaf(v0.x,K2,mn)) + __builtin_exp2f(__builtin_fmaf(v0.y,K2,mn))
    + __builtin_exp2f(__builtin_fmaf(v0.z,K2,mn)) + __builtin_exp2f(__builtin_fmaf(v0.w,K2,mn))
    + __builtin_exp2f(__builtin_fmaf(v1.x,K2,mn)) + __builtin_exp2f(__builtin_fmaf(v1.y,K2,mn))
    + __builtin_exp2f(__builtin_fmaf(v1.z,K2,mn)) + __builtin_exp2f(__builtin_fmaf(v1.w,K2,mn))
    + __builtin_exp2f(__builtin_fmaf(v2.x,K2,mn)) + __builtin_exp2f(__builtin_fmaf(v2.y,K2,mn))
    + __builtin_exp2f(__builtin_fmaf(v2.z,K2,mn)) + __builtin_exp2f(__builtin_fmaf(v2.w,K2,mn))
    + __builtin_exp2f(__builtin_fmaf(v3.x,K2,mn)) + __builtin_exp2f(__builtin_fmaf(v3.y,K2,mn))
    + __builtin_exp2f(__builtin_fmaf(v3.z,K2,mn)) + __builtin_exp2f(__builtin_fmaf(v3.w,K2,mn));
    s = wave_sum(s);

    if (lane == 0) {
        float lse = m + __builtin_log2f(s) * LN2;
        int b = row >> 10, t = row & (T_TOK - 1);
        bool valid = (t < alens[b]) && (tg != -100);
        float nll = 0.0f;
        if (valid) {
            int idx = min(max(tg - V_TEXT, 0), V_AUDIO - 1);
            nll = lse - p[idx];
        }
        nll_out[row] = nll;
    }
}

// ---------- producer helper: stage one 60-row chunk as LINEAR emissions ----
// Writes e = 2^{x*K2} (masked to 0 for cols >= k) into db, and accumulates
// the per-row softmax denominator  prod *= (sum_j e_j + e^-8)  as a
// mantissa-product with integer exponent accumulation.
// Row sums via pure-VALU DPP reduce (row_shr1/2/4/8 + row_bcast15): lane 31
// ends with the even row's 32-lane sum, lane 63 with the odd row's. prod is
// only meaningful on lanes 31 and 63 (combined via readlane at the end).
// No ds_swizzle: keeps the LDS pipe free and avoids 5-deep DS-latency chains.
__device__ __forceinline__ void stage_rows(
    float* db, const float* __restrict__ abase, int g0, int k, int q,
    int lane, float& prod, int& acc)
{
    int half = lane >> 5, col = (lane & 31) * 4;
    #pragma unroll 6
    for (int i = 0; i < CHK / 2; i++) {
        int r  = 2 * i + half;
        int rg = g0 + r;
        int rc = min(rg, TQ_ - 1);      // clamp: no OOB past attn
        float4 v = *reinterpret_cast<const float4*>(abase + (size_t)rc * TK_ + col);
        float e0 = (col + 0 < k) ? __builtin_exp2f(v.x * K2) : 0.0f;
        float e1 = (col + 1 < k) ? __builtin_exp2f(v.y * K2) : 0.0f;
        float e2 = (col + 2 < k) ? __builtin_exp2f(v.z * K2) : 0.0f;
        float e3 = (col + 3 < k) ? __builtin_exp2f(v.w * K2) : 0.0f;
        *reinterpret_cast<float4*>(db + r * TK_ + col) = make_float4(e0, e1, e2, e3);

        // row denominator: DPP tree (VALU only, ~independent across i)
        float ps = (e0 + e1) + (e2 + e3);
        ps += dpp_mov<0x111>(ps, 0.0f);   // row_shr:1
        ps += dpp_mov<0x112>(ps, 0.0f);   // row_shr:2
        ps += dpp_mov<0x114>(ps, 0.0f);   // row_shr:4
        ps += dpp_mov<0x118>(ps, 0.0f);   // row_shr:8  -> lane15/47 hold 16-sums
        ps += dpp_mov<0x142>(ps, 0.0f);   // row_bcast15 -> lane31/63 hold 32-sums
        ps += EM8;                        // + blank term 2^-EB8
        prod *= (rg < q) ? ps : 1.0f;
        if ((i % 3) == 2) {               // renorm every 3 multiplies (exact)
            int b = __float_as_int(prod);
            acc += (b >> 23) - 127;
            prod = __int_as_float((b & 0x007fffff) | 0x3f800000);
        }
    }
}

// ---------- Kernel 2: CTC recursion in SCALED LINEAR domain ----------
// Chain per step is add->add->mul (+DPP shift): no transcendentals on the
// critical path. exp2 of emissions is done by the producer wave (off-chain).
// Exact power-of-2 rescale every 8 steps keeps values in float range; the
// stripped exponents accumulate in Mtot. Softmax normalizer is folded into
// the producer (Csum).
__global__ __launch_bounds__(128) void rec_kernel(
    const float* __restrict__ attn,
    const int* __restrict__ src_lens, const int* __restrict__ out_lens,
    float* __restrict__ loss_out)
{
    __shared__ float buf[2][CHK][TK_];   // 61440 B (linear emissions)
    __shared__ float csh;                // producer -> consumer: Csum (log2)
    int n   = blockIdx.x;
    int tid = threadIdx.x;
    int wid = tid >> 6, lane = tid & 63;
    int k = min(src_lens[n >> 2], TK_);
    int q = min(out_lens[n >> 2], TQ_);
    int ncha = (q + CHK - 1) / CHK;
    const float* abase = attn + (size_t)n * TQ_ * TK_;

    // producer-side normalizer accumulators (valid on lanes 31/63)
    float prod = 1.0f;
    int   acc  = 0;

    // consumer state: lane l holds states 4l..4l+3 (p0..p3); p4 = state 256
    // (valid on lane 63). Virtual pre-state: p0=1 on lane 0 makes t=0 a
    // regular step, so every chunk runs uniformly.
    float p0 = (wid == 0 && lane == 0) ? 1.0f : 0.0f;
    float p1 = 0.0f, p2 = 0.0f, p3 = 0.0f, p4 = 0.0f, p3s = 0.0f;
    int   Mtot = 0;      // sum of stripped log2 scales
    int   rsc  = 0;      // rescale cadence counter (every 2 groups = 8 steps)

    if (wid == 1) stage_rows(&buf[0][0][0], abase, 0, k, q, lane, prod, acc);
    __syncthreads();

#define SSTEP(xv)                                                            \
    do {                                                                     \
        float c01 = p0 + p3s;          /* states s, s-1           */         \
        float c12 = p2 + p1;                                                 \
        float n4  = (p4 + p3) * EM8;   /* state 256 (blank)       */         \
        p0 = c01 * EM8;                /* even: blank emission    */         \
        p1 = (p1 + c01) * xv.x;        /* odd: 3-way + label col 2l   */     \
        p2 = c12 * EM8;                                                      \
        p3 = (p3 + c12) * xv.y;        /* odd: 3-way + label col 2l+1 */     \
        p4 = n4;                                                             \
        p3s = dpp_shr1_old(p3, 0.0f);  /* shift state 4l+3 -> lane l+1 */    \
    } while (0)

#define RESCALE()                                                            \
    do {                                                                     \
        float wm = fmaxf(fmaxf(fmaxf(p0, p1), fmaxf(p2, p3)),                \
                         fmaxf(p4, p3s));                                    \
        wm = wave_max(wm);                                                   \
        int ebits = __float_as_int(wm) & 0x7f800000;                         \
        if (ebits > 0) {               /* skip if all-zero/denormal */       \
            int se = 294 - (ebits >> 23);  /* park max at 2^40 */            \
            se = se < 1 ? 1 : (se > 254 ? 254 : se);                         \
            float sc = __int_as_float(se << 23);                             \
            Mtot += 127 - se;                                                \
            p0 *= sc; p1 *= sc; p2 *= sc; p3 *= sc; p4 *= sc; p3s *= sc;     \
        }                                                                    \
    } while (0)

    for (int c = 0; c < ncha; c++) {
        if (wid == 1) {
            if (c + 1 < ncha)
                stage_rows(&buf[(c + 1) & 1][0][0], abase, (c + 1) * CHK,
                           k, q, lane, prod, acc);
        } else {
            const float* lb = &buf[c & 1][0][2 * lane];
            int lim = min(CHK, q - c * CHK);
            int ts = 0;
            if (ts < lim) {
#define LD(j) (*reinterpret_cast<const float2*>(lb + min((j), CHK - 1) * TK_))
                float2 A = LD(0), Bv = LD(1), Cv = LD(2), Dv = LD(3);
                for (; ts + 4 <= lim; ts += 4) {
                    float2 nA = LD(ts + 4), nB = LD(ts + 5),
                           nC = LD(ts + 6), nD = LD(ts + 7);
                    SSTEP(A); SSTEP(Bv); SSTEP(Cv); SSTEP(Dv);
                    if (++rsc == 2) { rsc = 0; RESCALE(); }
                    A = nA; Bv = nB; Cv = nC; Dv = nD;
                }
                for (; ts < lim; ts++) { SSTEP(A); A = Bv; Bv = Cv; Cv = Dv; }
#undef LD
            }
        }
        __syncthreads();
    }
#undef SSTEP
#undef RESCALE

    if (wid == 1) {
        // Csum = (even-rows product, lane31) * (odd-rows product, lane63)
        float cl = __builtin_log2f(prod) + (float)acc;
        float cs = lane_bcast(cl, 31) + lane_bcast(cl, 63);
        if (lane == 0) csh = cs;
    }
    __syncthreads();

    if (wid == 0) {
        int s1 = 2 * k - 1, s2 = 2 * k;
        float e1v, e2v;
        {
            int l = s1 >> 2, r = s1 & 3;
            float c1 = __shfl(p1, l), c3 = __shfl(p3, l);
            e1v = (r == 1) ? c1 : c3;
        }
        if (s2 == 256) {
            e2v = __shfl(p4, 63);
        } else {
            int l = s2 >> 2, r = s2 & 3;
            float c0 = __shfl(p0, l), c2 = __shfl(p2, l);
            e2v = (r == 0) ? c0 : c2;
        }
        // log2 alpha_norm = log2(p) + Mtot - Csum
        float l2 = __builtin_log2f(e1v + e2v) + (float)Mtot - csh;
        float nll = -l2 * LN2;
        float loss = nll / (float)k;
        if (!(isfinite(loss) && loss < 1.0e8f)) loss = 0.0f;
        if (lane == 0) loss_out[n] = loss;
    }
}

// ---------- Kernel 3: finalize ----------
__global__ __launch_bounds__(256) void fin_kernel(
    const float* __restrict__ nll, const int* __restrict__ alens,
    const int* __restrict__ step, const float* __restrict__ attn_losses,
    float* __restrict__ out)
{
    __shared__ float red[4];
    int tid = threadIdx.x;
    float s = 0.0f;
    for (int i = tid; i < B_ * T_TOK; i += 256) s += nll[i];
    #pragma unroll
    for (int off = 32; off > 0; off >>= 1) s += __shfl_xor(s, off);
    if ((tid & 63) == 0) red[tid >> 6] = s;
    __syncthreads();
    if (tid == 0) {
        float ce_sum = red[0] + red[1] + red[2] + red[3];
        int denom = 0;
        for (int b = 0; b < B_; b++) denom += min(alens[b], T_TOK);
        denom = max(denom, 1);
        float token = ce_sum / (float)denom;
        float a = 0.0f;
        for (int i = 0; i < NSEQ; i++) a += attn_losses[i];
        a *= (1.0f / NSEQ);
        if (step[0] <= 5000) a = 0.0f;
        out[0] = 1.5f * token + 10.0f * a;
        out[1] = a;
        out[2] = token;
    }
}

extern "C" void kernel_launch(void* const* d_in, const int* in_sizes, int n_in,
                              void* d_out, int out_size, void* d_ws, size_t ws_size,
                              hipStream_t stream)
{
    const float* logits  = (const float*)d_in[0];
    const float* attn    = (const float*)d_in[1];
    const int*   targets = (const int*)d_in[2];
    const int*   alens   = (const int*)d_in[3];
    const int*   slens   = (const int*)d_in[4];
    const int*   olens   = (const int*)d_in[5];
    const int*   step    = (const int*)d_in[6];
    float* out = (float*)d_out;
    float* ws  = (float*)d_ws;

    float* ws_attn = ws;            // [0..31]
    float* ws_nll  = ws + 64;       // [64 .. 64+8192)

    ce_kernel <<<dim3(B_ * T_TOK / 4), dim3(256), 0, stream>>>(logits, targets, alens, ws_nll);
    rec_kernel<<<dim3(NSEQ),           dim3(128), 0, stream>>>(attn, slens, olens, ws_attn);
    fin_kernel<<<dim3(1),              dim3(256), 0, stream>>>(ws_nll, alens, step, ws_attn, out);
}

// Round 3
// 238.005 us; speedup vs baseline: 1.5177x; 1.1822x over previous
//
#include <hip/hip_runtime.h>
#include <hip/hip_bf16.h>
#include <cstdint>
#include <cstddef>

#define V_TEXT   256
#define V_TOTAL  4352
#define V_AUDIO  4096
#define B_       8
#define H_       4
#define TQ_      800
#define TK_      128
#define T_TOK    1024
#define NSEQ     32
#define K2       1.4426950408889634f   // 1/ln2
#define LN2      0.6931471805599453f
#define EB8      11.541560327111707f   // 8*K2  (blank log2-prob magnitude)
#define EM8      3.3546262790251185e-04f // e^-8 = 2^-EB8 (linear blank emission)
#define FNEGINF  (-3.0e38f)
#define CHK      30                    // timesteps per LDS chunk (30 KB dbuf)

// ---- DPP helpers (ctrl must be a compile-time constant) ----
template <int CTRL>
__device__ __forceinline__ float dpp_mov(float x, float old) {
    return __int_as_float(__builtin_amdgcn_update_dpp(
        __float_as_int(old), __float_as_int(x), CTRL, 0xf, 0xf, false));
}
__device__ __forceinline__ float dpp_shr1_old(float x, float old) {
    return dpp_mov<0x138>(x, old);      // wave_shr:1
}
__device__ __forceinline__ float lane_bcast(float x, int lane) {
    return __int_as_float(__builtin_amdgcn_readlane(__float_as_int(x), lane));
}
__device__ __forceinline__ float wave_max(float x) {
    x = fmaxf(x, dpp_mov<0x111>(x, FNEGINF));
    x = fmaxf(x, dpp_mov<0x112>(x, FNEGINF));
    x = fmaxf(x, dpp_mov<0x114>(x, FNEGINF));
    x = fmaxf(x, dpp_mov<0x118>(x, FNEGINF));
    x = fmaxf(x, dpp_mov<0x142>(x, FNEGINF));
    x = fmaxf(x, dpp_mov<0x143>(x, FNEGINF));
    return lane_bcast(x, 63);
}

// ---------- producer helper: stage 10 rows of one chunk (one of 3 waves) ---
// Issues ALL 5 float4 loads first (single latency exposure), then converts
// to linear emissions e = 2^{x*K2} (masked 0 for cols >= k), writes LDS, and
// accumulates the per-row softmax denominator prod *= (sum_j e_j + e^-8) as
// a mantissa-product with exact integer exponent accumulation.
// Row sums via pure-VALU DPP tree; prod valid on lanes 31 (even rows) and
// 63 (odd rows) only.
__device__ __forceinline__ void stage_rows3(
    float* db, const float* __restrict__ abase, int g0, int pw, int k, int q,
    int lane, float& prod, int& acc)
{
    int half = lane >> 5, col = (lane & 31) * 4;
    int i0 = pw * 5;                      // this wave's iteration window
    float4 v[5];
    #pragma unroll
    for (int u = 0; u < 5; u++) {
        int rc = min(g0 + 2 * (i0 + u) + half, TQ_ - 1);  // clamp: no OOB
        v[u] = *reinterpret_cast<const float4*>(abase + (size_t)rc * TK_ + col);
    }
    #pragma unroll
    for (int u = 0; u < 5; u++) {
        int r  = 2 * (i0 + u) + half;
        int rg = g0 + r;
        float e0 = (col + 0 < k) ? __builtin_exp2f(v[u].x * K2) : 0.0f;
        float e1 = (col + 1 < k) ? __builtin_exp2f(v[u].y * K2) : 0.0f;
        float e2 = (col + 2 < k) ? __builtin_exp2f(v[u].z * K2) : 0.0f;
        float e3 = (col + 3 < k) ? __builtin_exp2f(v[u].w * K2) : 0.0f;
        *reinterpret_cast<float4*>(db + r * TK_ + col) = make_float4(e0, e1, e2, e3);

        float ps = (e0 + e1) + (e2 + e3);
        ps += dpp_mov<0x111>(ps, 0.0f);   // row_shr:1
        ps += dpp_mov<0x112>(ps, 0.0f);   // row_shr:2
        ps += dpp_mov<0x114>(ps, 0.0f);   // row_shr:4
        ps += dpp_mov<0x118>(ps, 0.0f);   // row_shr:8
        ps += dpp_mov<0x142>(ps, 0.0f);   // row_bcast15 -> lanes 31/63: 32-sums
        ps += EM8;                        // + blank term
        prod *= (rg < q) ? ps : 1.0f;
        if (u & 1) {                      // exact renorm every 2 multiplies
            int b = __float_as_int(prod);
            acc += (b >> 23) - 127;
            prod = __int_as_float((b & 0x007fffff) | 0x3f800000);
        }
    }
}

// ---------- fused kernel: blocks [0,32) = CTC recursion, rest = CE rows ----
// rec: 4 waves; waves 1-3 stage chunk c+1 (10 rows each) while wave 0 runs
// the scaled-linear recursion on chunk c. CE blocks stream independently on
// the remaining CUs, overlapping the serial recursion in time.
__global__ __launch_bounds__(256) void fused_kernel(
    const float* __restrict__ logits, const int* __restrict__ targets,
    const int* __restrict__ alens,
    const float* __restrict__ attn, const int* __restrict__ slens,
    const int* __restrict__ olens,
    float* __restrict__ nll_out, float* __restrict__ loss_out)
{
    __shared__ float buf[2][CHK][TK_];   // 30720 B (linear emissions)
    __shared__ float cshp[4];            // producer Csum partials (log2)

    int tid = threadIdx.x;
    int wid = tid >> 6, lane = tid & 63;

    if (blockIdx.x >= NSEQ) {
        // ================= CE path: one wave per row =================
        int row = (blockIdx.x - NSEQ) * 4 + wid;
        const float* p = logits + (size_t)row * V_TOTAL + V_TEXT;

        float4 v0 = *reinterpret_cast<const float4*>(p + lane * 4);
        float4 v1 = *reinterpret_cast<const float4*>(p + lane * 4 + 1024);
        float4 v2 = *reinterpret_cast<const float4*>(p + lane * 4 + 2048);
        float4 v3 = *reinterpret_cast<const float4*>(p + lane * 4 + 3072);
        int tg = targets[row];

        float m = fmaxf(fmaxf(fmaxf(v0.x, v0.y), fmaxf(v0.z, v0.w)),
                        fmaxf(fmaxf(v1.x, v1.y), fmaxf(v1.z, v1.w)));
        m = fmaxf(m, fmaxf(fmaxf(v2.x, v2.y), fmaxf(v2.z, v2.w)));
        m = fmaxf(m, fmaxf(fmaxf(v3.x, v3.y), fmaxf(v3.z, v3.w)));
        m = wave_max(m);

        float mn = -m * K2;
        float s =
          __builtin_exp2f(__builtin_fmaf(v0.x,K2,mn)) + __builtin_exp2f(__builtin_fmaf(v0.y,K2,mn))
        + __builtin_exp2f(__builtin_fmaf(v0.z,K2,mn)) + __builtin_exp2f(__builtin_fmaf(v0.w,K2,mn))
        + __builtin_exp2f(__builtin_fmaf(v1.x,K2,mn)) + __builtin_exp2f(__builtin_fmaf(v1.y,K2,mn))
        + __builtin_exp2f(__builtin_fmaf(v1.z,K2,mn)) + __builtin_exp2f(__builtin_fmaf(v1.w,K2,mn))
        + __builtin_exp2f(__builtin_fmaf(v2.x,K2,mn)) + __builtin_exp2f(__builtin_fmaf(v2.y,K2,mn))
        + __builtin_exp2f(__builtin_fmaf(v2.z,K2,mn)) + __builtin_exp2f(__builtin_fmaf(v2.w,K2,mn))
        + __builtin_exp2f(__builtin_fmaf(v3.x,K2,mn)) + __builtin_exp2f(__builtin_fmaf(v3.y,K2,mn))
        + __builtin_exp2f(__builtin_fmaf(v3.z,K2,mn)) + __builtin_exp2f(__builtin_fmaf(v3.w,K2,mn));
        // wave sum via DPP
        s += dpp_mov<0x111>(s, 0.0f);
        s += dpp_mov<0x112>(s, 0.0f);
        s += dpp_mov<0x114>(s, 0.0f);
        s += dpp_mov<0x118>(s, 0.0f);
        s += dpp_mov<0x142>(s, 0.0f);
        s  = lane_bcast(s, 31) + lane_bcast(s, 63);

        if (lane == 0) {
            float lse = m + __builtin_log2f(s) * LN2;
            int b = row >> 10, t = row & (T_TOK - 1);
            bool valid = (t < alens[b]) && (tg != -100);
            float nll = 0.0f;
            if (valid) {
                int idx = min(max(tg - V_TEXT, 0), V_AUDIO - 1);
                nll = lse - p[idx];
            }
            nll_out[row] = nll;
        }
        return;
    }

    // ================= REC path =================
    int n = blockIdx.x;
    int k = min(slens[n >> 2], TK_);
    int q = min(olens[n >> 2], TQ_);
    int ncha = (q + CHK - 1) / CHK;
    const float* abase = attn + (size_t)n * TQ_ * TK_;

    float prod = 1.0f;   // producer normalizer (lanes 31/63)
    int   acc  = 0;

    // consumer state: lane l holds states 4l..4l+3 (p0..p3); p4 = state 256
    // (lane 63). Virtual pre-state p0=1 on lane 0 makes t=0 a regular step.
    float p0 = (wid == 0 && lane == 0) ? 1.0f : 0.0f;
    float p1 = 0.0f, p2 = 0.0f, p3 = 0.0f, p4 = 0.0f, p3s = 0.0f;
    int   Mtot = 0;      // sum of stripped log2 scales
    int   rsc  = 0;      // rescale cadence: every 2 groups = 8 steps

    if (wid > 0) stage_rows3(&buf[0][0][0], abase, 0, wid - 1, k, q, lane, prod, acc);
    __syncthreads();

#define SSTEP(xv)                                                            \
    do {                                                                     \
        float c01 = p0 + p3s;                                                \
        float c12 = p2 + p1;                                                 \
        float n4  = (p4 + p3) * EM8;                                         \
        p0 = c01 * EM8;                                                      \
        p1 = (p1 + c01) * xv.x;                                              \
        p2 = c12 * EM8;                                                      \
        p3 = (p3 + c12) * xv.y;                                              \
        p4 = n4;                                                             \
        p3s = dpp_shr1_old(p3, 0.0f);                                        \
    } while (0)

#define RESCALE()                                                            \
    do {                                                                     \
        float wm = fmaxf(fmaxf(fmaxf(p0, p1), fmaxf(p2, p3)),                \
                         fmaxf(p4, p3s));                                    \
        wm = wave_max(wm);                                                   \
        int ebits = __float_as_int(wm) & 0x7f800000;                         \
        if (ebits > 0) {               /* skip if all-zero/denormal */       \
            int se = 274 - (ebits >> 23);  /* park max at 2^20 */            \
            se = se < 1 ? 1 : (se > 254 ? 254 : se);                         \
            float sc = __int_as_float(se << 23);                             \
            Mtot += 127 - se;                                                \
            p0 *= sc; p1 *= sc; p2 *= sc; p3 *= sc; p4 *= sc; p3s *= sc;     \
        }                                                                    \
    } while (0)

    for (int c = 0; c < ncha; c++) {
        if (wid > 0) {
            if (c + 1 < ncha)
                stage_rows3(&buf[(c + 1) & 1][0][0], abase, (c + 1) * CHK,
                            wid - 1, k, q, lane, prod, acc);
        } else {
            const float* lb = &buf[c & 1][0][2 * lane];
            int lim = min(CHK, q - c * CHK);
            int ts = 0;
            if (ts < lim) {
#define LD(j) (*reinterpret_cast<const float2*>(lb + min((j), CHK - 1) * TK_))
                float2 A = LD(0), Bv = LD(1), Cv = LD(2), Dv = LD(3);
                for (; ts + 4 <= lim; ts += 4) {
                    float2 nA = LD(ts + 4), nB = LD(ts + 5),
                           nC = LD(ts + 6), nD = LD(ts + 7);
                    SSTEP(A); SSTEP(Bv); SSTEP(Cv); SSTEP(Dv);
                    if (++rsc == 2) { rsc = 0; RESCALE(); }
                    A = nA; Bv = nB; Cv = nC; Dv = nD;
                }
                for (; ts < lim; ts++) { SSTEP(A); A = Bv; Bv = Cv; Cv = Dv; }
#undef LD
            }
        }
        __syncthreads();
    }
#undef SSTEP
#undef RESCALE

    if (wid > 0) {
        // this wave's Csum partial = even-rows (lane31) * odd-rows (lane63)
        float cl = __builtin_log2f(prod) + (float)acc;
        float cs = lane_bcast(cl, 31) + lane_bcast(cl, 63);
        if (lane == 0) cshp[wid] = cs;
    }
    __syncthreads();

    if (wid == 0) {
        float csh = cshp[1] + cshp[2] + cshp[3];
        int s1 = 2 * k - 1, s2 = 2 * k;
        float e1v, e2v;
        {
            int l = s1 >> 2, r = s1 & 3;
            float c1 = __shfl(p1, l), c3 = __shfl(p3, l);
            e1v = (r == 1) ? c1 : c3;
        }
        if (s2 == 256) {
            e2v = __shfl(p4, 63);
        } else {
            int l = s2 >> 2, r = s2 & 3;
            float c0 = __shfl(p0, l), c2 = __shfl(p2, l);
            e2v = (r == 0) ? c0 : c2;
        }
        // log2 alpha_norm = log2(p) + Mtot - Csum
        float l2 = __builtin_log2f(e1v + e2v) + (float)Mtot - csh;
        float nll = -l2 * LN2;
        float loss = nll / (float)k;
        if (!(isfinite(loss) && loss < 1.0e8f)) loss = 0.0f;
        if (lane == 0) loss_out[n] = loss;
    }
}

// ---------- finalize ----------
__global__ __launch_bounds__(256) void fin_kernel(
    const float* __restrict__ nll, const int* __restrict__ alens,
    const int* __restrict__ step, const float* __restrict__ attn_losses,
    float* __restrict__ out)
{
    __shared__ float red[4];
    int tid = threadIdx.x;
    float s = 0.0f;
    for (int i = tid; i < B_ * T_TOK; i += 256) s += nll[i];
    #pragma unroll
    for (int off = 32; off > 0; off >>= 1) s += __shfl_xor(s, off);
    if ((tid & 63) == 0) red[tid >> 6] = s;
    __syncthreads();
    if (tid == 0) {
        float ce_sum = red[0] + red[1] + red[2] + red[3];
        int denom = 0;
        for (int b = 0; b < B_; b++) denom += min(alens[b], T_TOK);
        denom = max(denom, 1);
        float token = ce_sum / (float)denom;
        float a = 0.0f;
        for (int i = 0; i < NSEQ; i++) a += attn_losses[i];
        a *= (1.0f / NSEQ);
        if (step[0] <= 5000) a = 0.0f;
        out[0] = 1.5f * token + 10.0f * a;
        out[1] = a;
        out[2] = token;
    }
}

extern "C" void kernel_launch(void* const* d_in, const int* in_sizes, int n_in,
                              void* d_out, int out_size, void* d_ws, size_t ws_size,
                              hipStream_t stream)
{
    const float* logits  = (const float*)d_in[0];
    const float* attn    = (const float*)d_in[1];
    const int*   targets = (const int*)d_in[2];
    const int*   alens   = (const int*)d_in[3];
    const int*   slens   = (const int*)d_in[4];
    const int*   olens   = (const int*)d_in[5];
    const int*   step    = (const int*)d_in[6];
    float* out = (float*)d_out;
    float* ws  = (float*)d_ws;

    float* ws_attn = ws;            // [0..31]
    float* ws_nll  = ws + 64;       // [64 .. 64+8192)

    fused_kernel<<<dim3(NSEQ + B_ * T_TOK / 4), dim3(256), 0, stream>>>(
        logits, targets, alens, attn, slens, olens, ws_nll, ws_attn);
    fin_kernel<<<dim3(1), dim3(256), 0, stream>>>(ws_nll, alens, step, ws_attn, out);
}

// Round 4
// 237.000 us; speedup vs baseline: 1.5241x; 1.0042x over previous
//
#include <hip/hip_runtime.h>
#include <cstdint>
#include <cstddef>

#define V_TEXT   256
#define V_TOTAL  4352
#define V_AUDIO  4096
#define B_       8
#define TQ_      800
#define TK_      128
#define T_TOK    1024
#define NSEQ     32
#define K2       1.4426950408889634f   // 1/ln2
#define LN2      0.6931471805599453f
#define EM8      3.3546262790251185e-04f // e^-8 (linear blank emission)
#define FNEGINF  (-3.0e38f)
#define CHK      32                    // timesteps per LDS chunk (4 groups of 8)
#define NBUF     3                     // LDS ring depth (3*16KB = 48KB)

// ---- DPP helpers (ctrl must be a compile-time constant) ----
template <int CTRL>
__device__ __forceinline__ float dpp_mov(float x, float old) {
    return __int_as_float(__builtin_amdgcn_update_dpp(
        __float_as_int(old), __float_as_int(x), CTRL, 0xf, 0xf, false));
}
__device__ __forceinline__ float dpp_shr1_old(float x, float old) {
    return dpp_mov<0x138>(x, old);      // wave_shr:1
}
__device__ __forceinline__ float lane_bcast(float x, int lane) {
    return __int_as_float(__builtin_amdgcn_readlane(__float_as_int(x), lane));
}
__device__ __forceinline__ float wave_max(float x) {
    x = fmaxf(x, dpp_mov<0x111>(x, FNEGINF));
    x = fmaxf(x, dpp_mov<0x112>(x, FNEGINF));
    x = fmaxf(x, dpp_mov<0x114>(x, FNEGINF));
    x = fmaxf(x, dpp_mov<0x118>(x, FNEGINF));
    x = fmaxf(x, dpp_mov<0x142>(x, FNEGINF));
    x = fmaxf(x, dpp_mov<0x143>(x, FNEGINF));
    return lane_bcast(x, 63);
}

// ---------- producer: issue the 6 float4 loads for one chunk-third ----------
// Each producer wave pw (0..2) covers 2-row iterations [pw*5, pw*5+6) of the
// 16 iterations in a 32-row chunk (overlap at 5/10 is benign: same data).
__device__ __forceinline__ void load6(float4* v, const float* __restrict__ abase,
                                      int g0, int pw, int lane) {
    int half = lane >> 5, col = (lane & 31) * 4;
    int i0 = pw * 5;
    #pragma unroll
    for (int u = 0; u < 6; u++) {
        int rc = min(g0 + 2 * (i0 + u) + half, TQ_ - 1);   // clamp: no OOB
        v[u] = *reinterpret_cast<const float4*>(abase + (size_t)rc * TK_ + col);
    }
}

// ---------- producer: exp2 + LDS write + Csum accumulation for one third ---
// Emissions e = 2^{x*K2} (0 for cols >= k). Per-row softmax denominator
// prod *= (sum_j e_j + e^-8) as mantissa-product with exact integer exponent
// accumulation; row sums via pure-VALU DPP tree (valid lanes 31/63).
// Ownership mask de-duplicates the overlapped iterations (5 and 10).
__device__ __forceinline__ void write6(float* db, const float4* v, int g0, int pw,
                                       int k, int q, int lane, float& prod, int& acc) {
    int half = lane >> 5, col = (lane & 31) * 4;
    int i0 = pw * 5;
    #pragma unroll
    for (int u = 0; u < 6; u++) {
        int r  = 2 * (i0 + u) + half;
        int rg = g0 + r;
        float e0 = (col + 0 < k) ? __builtin_exp2f(v[u].x * K2) : 0.0f;
        float e1 = (col + 1 < k) ? __builtin_exp2f(v[u].y * K2) : 0.0f;
        float e2 = (col + 2 < k) ? __builtin_exp2f(v[u].z * K2) : 0.0f;
        float e3 = (col + 3 < k) ? __builtin_exp2f(v[u].w * K2) : 0.0f;
        *reinterpret_cast<float4*>(db + r * TK_ + col) = make_float4(e0, e1, e2, e3);

        float ps = (e0 + e1) + (e2 + e3);
        ps += dpp_mov<0x111>(ps, 0.0f);   // row_shr:1
        ps += dpp_mov<0x112>(ps, 0.0f);   // row_shr:2
        ps += dpp_mov<0x114>(ps, 0.0f);   // row_shr:4
        ps += dpp_mov<0x118>(ps, 0.0f);   // row_shr:8
        ps += dpp_mov<0x142>(ps, 0.0f);   // row_bcast15 -> lanes 31/63
        ps += EM8;                        // + blank term
        bool owned = (u < 5) || (pw == 2);
        prod *= (owned && rg < q) ? ps : 1.0f;
        if (u & 1) {                      // exact renorm every 2 multiplies
            int b = __float_as_int(prod);
            acc += (b >> 23) - 127;
            prod = __int_as_float((b & 0x007fffff) | 0x3f800000);
        }
    }
}

// ---------- fused kernel: blocks [0,32) = CTC recursion, rest = CE rows ----
__global__ __launch_bounds__(256) void fused_kernel(
    const float* __restrict__ logits, const int* __restrict__ targets,
    const int* __restrict__ alens,
    const float* __restrict__ attn, const int* __restrict__ slens,
    const int* __restrict__ olens,
    float* __restrict__ nll_out, float* __restrict__ loss_out)
{
    __shared__ float buf[NBUF][CHK][TK_];   // 49152 B (linear emissions)
    __shared__ float cshp[4];               // producer Csum partials (log2)

    int tid = threadIdx.x;
    int wid = tid >> 6, lane = tid & 63;

    if (blockIdx.x >= NSEQ) {
        // ================= CE path: one wave per row =================
        int row = (blockIdx.x - NSEQ) * 4 + wid;
        const float* p = logits + (size_t)row * V_TOTAL + V_TEXT;

        float4 v0 = *reinterpret_cast<const float4*>(p + lane * 4);
        float4 v1 = *reinterpret_cast<const float4*>(p + lane * 4 + 1024);
        float4 v2 = *reinterpret_cast<const float4*>(p + lane * 4 + 2048);
        float4 v3 = *reinterpret_cast<const float4*>(p + lane * 4 + 3072);
        int tg = targets[row];

        float m = fmaxf(fmaxf(fmaxf(v0.x, v0.y), fmaxf(v0.z, v0.w)),
                        fmaxf(fmaxf(v1.x, v1.y), fmaxf(v1.z, v1.w)));
        m = fmaxf(m, fmaxf(fmaxf(v2.x, v2.y), fmaxf(v2.z, v2.w)));
        m = fmaxf(m, fmaxf(fmaxf(v3.x, v3.y), fmaxf(v3.z, v3.w)));
        m = wave_max(m);

        float mn = -m * K2;
        float s =
          __builtin_exp2f(__builtin_fmaf(v0.x,K2,mn)) + __builtin_exp2f(__builtin_fmaf(v0.y,K2,mn))
        + __builtin_exp2f(__builtin_fmaf(v0.z,K2,mn)) + __builtin_exp2f(__builtin_fmaf(v0.w,K2,mn))
        + __builtin_exp2f(__builtin_fmaf(v1.x,K2,mn)) + __builtin_exp2f(__builtin_fmaf(v1.y,K2,mn))
        + __builtin_exp2f(__builtin_fmaf(v1.z,K2,mn)) + __builtin_exp2f(__builtin_fmaf(v1.w,K2,mn))
        + __builtin_exp2f(__builtin_fmaf(v2.x,K2,mn)) + __builtin_exp2f(__builtin_fmaf(v2.y,K2,mn))
        + __builtin_exp2f(__builtin_fmaf(v2.z,K2,mn)) + __builtin_exp2f(__builtin_fmaf(v2.w,K2,mn))
        + __builtin_exp2f(__builtin_fmaf(v3.x,K2,mn)) + __builtin_exp2f(__builtin_fmaf(v3.y,K2,mn))
        + __builtin_exp2f(__builtin_fmaf(v3.z,K2,mn)) + __builtin_exp2f(__builtin_fmaf(v3.w,K2,mn));
        s += dpp_mov<0x111>(s, 0.0f);
        s += dpp_mov<0x112>(s, 0.0f);
        s += dpp_mov<0x114>(s, 0.0f);
        s += dpp_mov<0x118>(s, 0.0f);
        s += dpp_mov<0x142>(s, 0.0f);
        s  = lane_bcast(s, 31) + lane_bcast(s, 63);

        if (lane == 0) {
            float lse = m + __builtin_log2f(s) * LN2;
            int b = row >> 10, t = row & (T_TOK - 1);
            bool valid = (t < alens[b]) && (tg != -100);
            float nll = 0.0f;
            if (valid) {
                int idx = min(max(tg - V_TEXT, 0), V_AUDIO - 1);
                nll = lse - p[idx];
            }
            nll_out[row] = nll;
        }
        return;
    }

    // ================= REC path =================
    int n = blockIdx.x;
    int k = min(slens[n >> 2], TK_);
    int q = min(olens[n >> 2], TQ_);
    int ncha = (q + CHK - 1) / CHK;          // >= 13 (q >= 400)
    const float* abase = attn + (size_t)n * TQ_ * TK_;

    float prod = 1.0f;   // producer normalizer (lanes 31/63)
    int   acc  = 0;

    // consumer state: lane l holds states 4l..4l+3 (p0..p3); p4 = state 256
    // (lane 63). Virtual pre-state p0=1 on lane 0 makes t=0 a regular step.
    float p0 = (wid == 0 && lane == 0) ? 1.0f : 0.0f;
    float p1 = 0.0f, p2 = 0.0f, p3 = 0.0f, p4 = 0.0f, p3s = 0.0f;
    int   Mtot = 0;      // sum of stripped log2 scales

    float4 R0[6], R1[6];  // producer double reg-set: chunk m lives in R[m&1]

    if (wid > 0) {
        // prologue: chunks 0,1 -> regs; write chunk 0; load chunk 2.
        load6(R0, abase, 0,       wid - 1, lane);
        load6(R1, abase, CHK,     wid - 1, lane);
        write6(&buf[0][0][0], R0, 0, wid - 1, k, q, lane, prod, acc);
        load6(R0, abase, 2 * CHK, wid - 1, lane);
    }
    __syncthreads();

#define SSTEP(xv)                                                            \
    do {                                                                     \
        float c01 = p0 + p3s;                                                \
        float c12 = p2 + p1;                                                 \
        float n4  = (p4 + p3) * EM8;                                         \
        p0 = c01 * EM8;                                                      \
        p1 = (p1 + c01) * xv.x;                                              \
        p2 = c12 * EM8;                                                      \
        p3 = (p3 + c12) * xv.y;                                              \
        p4 = n4;                                                             \
        p3s = dpp_shr1_old(p3, 0.0f);                                        \
    } while (0)

    for (int c = 0; c < ncha; c++) {
        if (wid > 0) {
            // window c: write chunk c+1 (loaded 2 windows ago), then issue
            // loads for chunk c+3 (written in window c+2 -> 2-window slack).
            if (c + 1 < ncha) {
                float* db = &buf[(c + 1) % NBUF][0][0];
                if ((c + 1) & 1) write6(db, R1, (c + 1) * CHK, wid - 1, k, q, lane, prod, acc);
                else             write6(db, R0, (c + 1) * CHK, wid - 1, k, q, lane, prod, acc);
            }
            if (c + 3 < ncha) {
                if ((c + 3) & 1) load6(R1, abase, (c + 3) * CHK, wid - 1, lane);
                else             load6(R0, abase, (c + 3) * CHK, wid - 1, lane);
            }
        } else {
            const float* lb = &buf[c % NBUF][0][2 * lane];
            int lim = min(CHK, q - c * CHK);
            int nfull = lim >> 3, rem = lim & 7;
            float2 cur[8], nxt[8];
            #pragma unroll
            for (int j = 0; j < 8; j++)
                cur[j] = *reinterpret_cast<const float2*>(lb + min(j, CHK - 1) * TK_);
            for (int g = 0; g < nfull; g++) {
                int base = g * 8;
                #pragma unroll
                for (int j = 0; j < 8; j++)
                    nxt[j] = *reinterpret_cast<const float2*>(lb + min(base + 8 + j, CHK - 1) * TK_);
                // off-chain rescale: snapshot max BEFORE the group; the DPP
                // tree overlaps the 8 SSTEPs; apply power-of-2 scale after.
                float wm = fmaxf(fmaxf(fmaxf(p0, p1), fmaxf(p2, p3)),
                                 fmaxf(p4, p3s));
                #pragma unroll
                for (int j = 0; j < 8; j++) SSTEP(cur[j]);
                wm = fmaxf(wm, dpp_mov<0x111>(wm, FNEGINF));
                wm = fmaxf(wm, dpp_mov<0x112>(wm, FNEGINF));
                wm = fmaxf(wm, dpp_mov<0x114>(wm, FNEGINF));
                wm = fmaxf(wm, dpp_mov<0x118>(wm, FNEGINF));
                wm = fmaxf(wm, dpp_mov<0x142>(wm, FNEGINF));
                wm = fmaxf(wm, dpp_mov<0x143>(wm, FNEGINF));
                wm = lane_bcast(wm, 63);
                int ebits = __float_as_int(wm) & 0x7f800000;
                if (ebits > 0) {            // park snapshot-max at 2^-32:
                    int se = 222 - (ebits >> 23);   // bounds: |p| <= 2^123
                    se = se < 1 ? 1 : (se > 254 ? 254 : se);
                    float sc = __int_as_float(se << 23);
                    Mtot += 127 - se;
                    p0 *= sc; p1 *= sc; p2 *= sc; p3 *= sc; p4 *= sc; p3s *= sc;
                }
                #pragma unroll
                for (int j = 0; j < 8; j++) cur[j] = nxt[j];
            }
            #pragma unroll
            for (int j = 0; j < 8; j++) if (j < rem) SSTEP(cur[j]);
        }
        __syncthreads();
    }
#undef SSTEP

    if (wid > 0) {
        // Csum partial = even-rows (lane31) * odd-rows (lane63)
        float cl = __builtin_log2f(prod) + (float)acc;
        float cs = lane_bcast(cl, 31) + lane_bcast(cl, 63);
        if (lane == 0) cshp[wid] = cs;
    }
    __syncthreads();

    if (wid == 0) {
        float csh = cshp[1] + cshp[2] + cshp[3];
        int s1 = 2 * k - 1, s2 = 2 * k;
        float e1v, e2v;
        {
            int l = s1 >> 2, r = s1 & 3;
            float c1 = __shfl(p1, l), c3 = __shfl(p3, l);
            e1v = (r == 1) ? c1 : c3;
        }
        if (s2 == 256) {
            e2v = __shfl(p4, 63);
        } else {
            int l = s2 >> 2, r = s2 & 3;
            float c0 = __shfl(p0, l), c2 = __shfl(p2, l);
            e2v = (r == 0) ? c0 : c2;
        }
        // log2 alpha_norm = log2(p) + Mtot - Csum
        float l2 = __builtin_log2f(e1v + e2v) + (float)Mtot - csh;
        float nll = -l2 * LN2;
        float loss = nll / (float)k;
        if (!(isfinite(loss) && loss < 1.0e8f)) loss = 0.0f;
        if (lane == 0) loss_out[n] = loss;
    }
}

// ---------- finalize ----------
__global__ __launch_bounds__(256) void fin_kernel(
    const float* __restrict__ nll, const int* __restrict__ alens,
    const int* __restrict__ step, const float* __restrict__ attn_losses,
    float* __restrict__ out)
{
    __shared__ float red[4];
    int tid = threadIdx.x;
    float s = 0.0f;
    for (int i = tid; i < B_ * T_TOK; i += 256) s += nll[i];
    #pragma unroll
    for (int off = 32; off > 0; off >>= 1) s += __shfl_xor(s, off);
    if ((tid & 63) == 0) red[tid >> 6] = s;
    __syncthreads();
    if (tid == 0) {
        float ce_sum = red[0] + red[1] + red[2] + red[3];
        int denom = 0;
        for (int b = 0; b < B_; b++) denom += min(alens[b], T_TOK);
        denom = max(denom, 1);
        float token = ce_sum / (float)denom;
        float a = 0.0f;
        for (int i = 0; i < NSEQ; i++) a += attn_losses[i];
        a *= (1.0f / NSEQ);
        if (step[0] <= 5000) a = 0.0f;
        out[0] = 1.5f * token + 10.0f * a;
        out[1] = a;
        out[2] = token;
    }
}

extern "C" void kernel_launch(void* const* d_in, const int* in_sizes, int n_in,
                              void* d_out, int out_size, void* d_ws, size_t ws_size,
                              hipStream_t stream)
{
    const float* logits  = (const float*)d_in[0];
    const float* attn    = (const float*)d_in[1];
    const int*   targets = (const int*)d_in[2];
    const int*   alens   = (const int*)d_in[3];
    const int*   slens   = (const int*)d_in[4];
    const int*   olens   = (const int*)d_in[5];
    const int*   step    = (const int*)d_in[6];
    float* out = (float*)d_out;
    float* ws  = (float*)d_ws;

    float* ws_attn = ws;            // [0..31]
    float* ws_nll  = ws + 64;       // [64 .. 64+8192)

    fused_kernel<<<dim3(NSEQ + B_ * T_TOK / 4), dim3(256), 0, stream>>>(
        logits, targets, alens, attn, slens, olens, ws_nll, ws_attn);
    fin_kernel<<<dim3(1), dim3(256), 0, stream>>>(ws_nll, alens, step, ws_attn, out);
}

// Round 5
// 236.881 us; speedup vs baseline: 1.5249x; 1.0005x over previous
//
#include <hip/hip_runtime.h>
#include <cstdint>
#include <cstddef>

#define V_TEXT   256
#define V_TOTAL  4352
#define V_AUDIO  4096
#define B_       8
#define TQ_      800
#define TK_      128
#define T_TOK    1024
#define NSEQ     32
#define K2       1.4426950408889634f   // 1/ln2
#define LN2      0.6931471805599453f
#define EM8      3.3546262790251185e-04f // e^-8 (linear blank emission)
#define FNEGINF  (-3.0e38f)
#define CHK      32                    // timesteps per LDS chunk (4 groups of 8)
#define NBUF     3                     // LDS ring depth (3*16KB = 48KB)

// ---- DPP helpers (ctrl must be a compile-time constant) ----
template <int CTRL>
__device__ __forceinline__ float dpp_mov(float x, float old) {
    return __int_as_float(__builtin_amdgcn_update_dpp(
        __float_as_int(old), __float_as_int(x), CTRL, 0xf, 0xf, false));
}
__device__ __forceinline__ float dpp_shr1_old(float x, float old) {
    return dpp_mov<0x138>(x, old);      // wave_shr:1
}
__device__ __forceinline__ float lane_bcast(float x, int lane) {
    return __int_as_float(__builtin_amdgcn_readlane(__float_as_int(x), lane));
}
__device__ __forceinline__ float wave_max(float x) {
    x = fmaxf(x, dpp_mov<0x111>(x, FNEGINF));
    x = fmaxf(x, dpp_mov<0x112>(x, FNEGINF));
    x = fmaxf(x, dpp_mov<0x114>(x, FNEGINF));
    x = fmaxf(x, dpp_mov<0x118>(x, FNEGINF));
    x = fmaxf(x, dpp_mov<0x142>(x, FNEGINF));
    x = fmaxf(x, dpp_mov<0x143>(x, FNEGINF));
    return lane_bcast(x, 63);
}

// ---- LDS-only barrier: drains lgkmcnt but NOT vmcnt, so producer global
// loads stay in flight across windows. __syncthreads() would emit
// s_waitcnt vmcnt(0) and serialize every window on HBM latency (the r1-r4
// ~180-300 cy/step floor). "memory" clobbers pin LDS-op ordering.
__device__ __forceinline__ void lds_barrier() {
    asm volatile("s_waitcnt lgkmcnt(0)" ::: "memory");
    __builtin_amdgcn_s_barrier();
    asm volatile("" ::: "memory");
}

// ---------- producer: issue the 6 float4 loads for one chunk-third ----------
// Each producer wave pw (0..2) covers 2-row iterations [pw*5, pw*5+6) of the
// 16 iterations in a 32-row chunk (overlap at 5/10 is benign: same data).
__device__ __forceinline__ void load6(float4* v, const float* __restrict__ abase,
                                      int g0, int pw, int lane) {
    int half = lane >> 5, col = (lane & 31) * 4;
    int i0 = pw * 5;
    #pragma unroll
    for (int u = 0; u < 6; u++) {
        int rc = min(g0 + 2 * (i0 + u) + half, TQ_ - 1);   // clamp: no OOB
        v[u] = *reinterpret_cast<const float4*>(abase + (size_t)rc * TK_ + col);
    }
}

// ---------- producer: exp2 + LDS write + Csum accumulation for one third ---
// Emissions e = 2^{x*K2} (0 for cols >= k). Per-row softmax denominator
// prod *= (sum_j e_j + e^-8) as mantissa-product with exact integer exponent
// accumulation; row sums via pure-VALU DPP tree (valid lanes 31/63).
// Ownership mask de-duplicates the overlapped iterations (5 and 10).
__device__ __forceinline__ void write6(float* db, const float4* v, int g0, int pw,
                                       int k, int q, int lane, float& prod, int& acc) {
    int half = lane >> 5, col = (lane & 31) * 4;
    int i0 = pw * 5;
    #pragma unroll
    for (int u = 0; u < 6; u++) {
        int r  = 2 * (i0 + u) + half;
        int rg = g0 + r;
        float e0 = (col + 0 < k) ? __builtin_exp2f(v[u].x * K2) : 0.0f;
        float e1 = (col + 1 < k) ? __builtin_exp2f(v[u].y * K2) : 0.0f;
        float e2 = (col + 2 < k) ? __builtin_exp2f(v[u].z * K2) : 0.0f;
        float e3 = (col + 3 < k) ? __builtin_exp2f(v[u].w * K2) : 0.0f;
        *reinterpret_cast<float4*>(db + r * TK_ + col) = make_float4(e0, e1, e2, e3);

        float ps = (e0 + e1) + (e2 + e3);
        ps += dpp_mov<0x111>(ps, 0.0f);   // row_shr:1
        ps += dpp_mov<0x112>(ps, 0.0f);   // row_shr:2
        ps += dpp_mov<0x114>(ps, 0.0f);   // row_shr:4
        ps += dpp_mov<0x118>(ps, 0.0f);   // row_shr:8
        ps += dpp_mov<0x142>(ps, 0.0f);   // row_bcast15 -> lanes 31/63
        ps += EM8;                        // + blank term
        bool owned = (u < 5) || (pw == 2);
        prod *= (owned && rg < q) ? ps : 1.0f;
        if (u & 1) {                      // exact renorm every 2 multiplies
            int b = __float_as_int(prod);
            acc += (b >> 23) - 127;
            prod = __int_as_float((b & 0x007fffff) | 0x3f800000);
        }
    }
}

// ---------- fused kernel: blocks [0,32) = CTC recursion, rest = CE rows ----
__global__ __launch_bounds__(256) void fused_kernel(
    const float* __restrict__ logits, const int* __restrict__ targets,
    const int* __restrict__ alens,
    const float* __restrict__ attn, const int* __restrict__ slens,
    const int* __restrict__ olens,
    float* __restrict__ nll_out, float* __restrict__ loss_out)
{
    __shared__ float buf[NBUF][CHK][TK_];   // 49152 B (linear emissions)
    __shared__ float cshp[4];               // producer Csum partials (log2)

    int tid = threadIdx.x;
    int wid = tid >> 6, lane = tid & 63;

    if (blockIdx.x >= NSEQ) {
        // ================= CE path: one wave per row =================
        int row = (blockIdx.x - NSEQ) * 4 + wid;
        const float* p = logits + (size_t)row * V_TOTAL + V_TEXT;

        float4 v0 = *reinterpret_cast<const float4*>(p + lane * 4);
        float4 v1 = *reinterpret_cast<const float4*>(p + lane * 4 + 1024);
        float4 v2 = *reinterpret_cast<const float4*>(p + lane * 4 + 2048);
        float4 v3 = *reinterpret_cast<const float4*>(p + lane * 4 + 3072);
        int tg = targets[row];

        float m = fmaxf(fmaxf(fmaxf(v0.x, v0.y), fmaxf(v0.z, v0.w)),
                        fmaxf(fmaxf(v1.x, v1.y), fmaxf(v1.z, v1.w)));
        m = fmaxf(m, fmaxf(fmaxf(v2.x, v2.y), fmaxf(v2.z, v2.w)));
        m = fmaxf(m, fmaxf(fmaxf(v3.x, v3.y), fmaxf(v3.z, v3.w)));
        m = wave_max(m);

        float mn = -m * K2;
        float s =
          __builtin_exp2f(__builtin_fmaf(v0.x,K2,mn)) + __builtin_exp2f(__builtin_fmaf(v0.y,K2,mn))
        + __builtin_exp2f(__builtin_fmaf(v0.z,K2,mn)) + __builtin_exp2f(__builtin_fmaf(v0.w,K2,mn))
        + __builtin_exp2f(__builtin_fmaf(v1.x,K2,mn)) + __builtin_exp2f(__builtin_fmaf(v1.y,K2,mn))
        + __builtin_exp2f(__builtin_fmaf(v1.z,K2,mn)) + __builtin_exp2f(__builtin_fmaf(v1.w,K2,mn))
        + __builtin_exp2f(__builtin_fmaf(v2.x,K2,mn)) + __builtin_exp2f(__builtin_fmaf(v2.y,K2,mn))
        + __builtin_exp2f(__builtin_fmaf(v2.z,K2,mn)) + __builtin_exp2f(__builtin_fmaf(v2.w,K2,mn))
        + __builtin_exp2f(__builtin_fmaf(v3.x,K2,mn)) + __builtin_exp2f(__builtin_fmaf(v3.y,K2,mn))
        + __builtin_exp2f(__builtin_fmaf(v3.z,K2,mn)) + __builtin_exp2f(__builtin_fmaf(v3.w,K2,mn));
        s += dpp_mov<0x111>(s, 0.0f);
        s += dpp_mov<0x112>(s, 0.0f);
        s += dpp_mov<0x114>(s, 0.0f);
        s += dpp_mov<0x118>(s, 0.0f);
        s += dpp_mov<0x142>(s, 0.0f);
        s  = lane_bcast(s, 31) + lane_bcast(s, 63);

        if (lane == 0) {
            float lse = m + __builtin_log2f(s) * LN2;
            int b = row >> 10, t = row & (T_TOK - 1);
            bool valid = (t < alens[b]) && (tg != -100);
            float nll = 0.0f;
            if (valid) {
                int idx = min(max(tg - V_TEXT, 0), V_AUDIO - 1);
                nll = lse - p[idx];
            }
            nll_out[row] = nll;
        }
        return;
    }

    // ================= REC path =================
    int n = blockIdx.x;
    int k = min(slens[n >> 2], TK_);
    int q = min(olens[n >> 2], TQ_);
    int ncha = (q + CHK - 1) / CHK;          // >= 13 (q >= 400)
    const float* abase = attn + (size_t)n * TQ_ * TK_;

    float prod = 1.0f;   // producer normalizer (lanes 31/63)
    int   acc  = 0;

    // consumer state: lane l holds states 4l..4l+3 (p0..p3); p4 = state 256
    // (lane 63). Virtual pre-state p0=1 on lane 0 makes t=0 a regular step.
    float p0 = (wid == 0 && lane == 0) ? 1.0f : 0.0f;
    float p1 = 0.0f, p2 = 0.0f, p3 = 0.0f, p4 = 0.0f, p3s = 0.0f;
    int   Mtot = 0;      // sum of stripped log2 scales

    float4 R0[6], R1[6];  // producer double reg-set: chunk m lives in R[m&1]

    if (wid > 0) {
        // prologue: chunks 0,1 -> regs; write chunk 0; load chunk 2.
        load6(R0, abase, 0,       wid - 1, lane);
        load6(R1, abase, CHK,     wid - 1, lane);
        write6(&buf[0][0][0], R0, 0, wid - 1, k, q, lane, prod, acc);
        load6(R0, abase, 2 * CHK, wid - 1, lane);
    }
    lds_barrier();       // loads for chunks 1,2 stay in flight

#define SSTEP(xv)                                                            \
    do {                                                                     \
        float c01 = p0 + p3s;                                                \
        float c12 = p2 + p1;                                                 \
        float n4  = (p4 + p3) * EM8;                                         \
        p0 = c01 * EM8;                                                      \
        p1 = (p1 + c01) * xv.x;                                              \
        p2 = c12 * EM8;                                                      \
        p3 = (p3 + c12) * xv.y;                                              \
        p4 = n4;                                                             \
        p3s = dpp_shr1_old(p3, 0.0f);                                        \
    } while (0)

    for (int c = 0; c < ncha; c++) {
        if (wid > 0) {
            // window c: write chunk c+1 (loaded 2 windows ago; compiler
            // inserts the counted vmcnt wait before the register use), then
            // issue loads for chunk c+3 -> they stay in flight across the
            // lds_barrier (no vmcnt drain).
            if (c + 1 < ncha) {
                float* db = &buf[(c + 1) % NBUF][0][0];
                if ((c + 1) & 1) write6(db, R1, (c + 1) * CHK, wid - 1, k, q, lane, prod, acc);
                else             write6(db, R0, (c + 1) * CHK, wid - 1, k, q, lane, prod, acc);
            }
            if (c + 3 < ncha) {
                if ((c + 3) & 1) load6(R1, abase, (c + 3) * CHK, wid - 1, lane);
                else             load6(R0, abase, (c + 3) * CHK, wid - 1, lane);
            }
        } else {
            const float* lb = &buf[c % NBUF][0][2 * lane];
            int lim = min(CHK, q - c * CHK);
            int nfull = lim >> 3, rem = lim & 7;
            float2 cur[8], nxt[8];
            #pragma unroll
            for (int j = 0; j < 8; j++)
                cur[j] = *reinterpret_cast<const float2*>(lb + min(j, CHK - 1) * TK_);
            for (int g = 0; g < nfull; g++) {
                int base = g * 8;
                #pragma unroll
                for (int j = 0; j < 8; j++)
                    nxt[j] = *reinterpret_cast<const float2*>(lb + min(base + 8 + j, CHK - 1) * TK_);
                // off-chain rescale: snapshot max BEFORE the group; the DPP
                // tree overlaps the 8 SSTEPs; apply power-of-2 scale after.
                float wm = fmaxf(fmaxf(fmaxf(p0, p1), fmaxf(p2, p3)),
                                 fmaxf(p4, p3s));
                #pragma unroll
                for (int j = 0; j < 8; j++) SSTEP(cur[j]);
                wm = fmaxf(wm, dpp_mov<0x111>(wm, FNEGINF));
                wm = fmaxf(wm, dpp_mov<0x112>(wm, FNEGINF));
                wm = fmaxf(wm, dpp_mov<0x114>(wm, FNEGINF));
                wm = fmaxf(wm, dpp_mov<0x118>(wm, FNEGINF));
                wm = fmaxf(wm, dpp_mov<0x142>(wm, FNEGINF));
                wm = fmaxf(wm, dpp_mov<0x143>(wm, FNEGINF));
                wm = lane_bcast(wm, 63);
                int ebits = __float_as_int(wm) & 0x7f800000;
                if (ebits > 0) {            // park snapshot-max at 2^-32:
                    int se = 222 - (ebits >> 23);   // bounds: |p| <= 2^123
                    se = se < 1 ? 1 : (se > 254 ? 254 : se);
                    float sc = __int_as_float(se << 23);
                    Mtot += 127 - se;
                    p0 *= sc; p1 *= sc; p2 *= sc; p3 *= sc; p4 *= sc; p3s *= sc;
                }
                #pragma unroll
                for (int j = 0; j < 8; j++) cur[j] = nxt[j];
            }
            #pragma unroll
            for (int j = 0; j < 8; j++) if (j < rem) SSTEP(cur[j]);
        }
        lds_barrier();    // LDS drained; global loads remain outstanding
    }
#undef SSTEP

    if (wid > 0) {
        // Csum partial = even-rows (lane31) * odd-rows (lane63)
        float cl = __builtin_log2f(prod) + (float)acc;
        float cs = lane_bcast(cl, 31) + lane_bcast(cl, 63);
        if (lane == 0) cshp[wid] = cs;
    }
    __syncthreads();      // vmcnt already 0 here; full drain is free

    if (wid == 0) {
        float csh = cshp[1] + cshp[2] + cshp[3];
        int s1 = 2 * k - 1, s2 = 2 * k;
        float e1v, e2v;
        {
            int l = s1 >> 2, r = s1 & 3;
            float c1 = __shfl(p1, l), c3 = __shfl(p3, l);
            e1v = (r == 1) ? c1 : c3;
        }
        if (s2 == 256) {
            e2v = __shfl(p4, 63);
        } else {
            int l = s2 >> 2, r = s2 & 3;
            float c0 = __shfl(p0, l), c2 = __shfl(p2, l);
            e2v = (r == 0) ? c0 : c2;
        }
        // log2 alpha_norm = log2(p) + Mtot - Csum
        float l2 = __builtin_log2f(e1v + e2v) + (float)Mtot - csh;
        float nll = -l2 * LN2;
        float loss = nll / (float)k;
        if (!(isfinite(loss) && loss < 1.0e8f)) loss = 0.0f;
        if (lane == 0) loss_out[n] = loss;
    }
}

// ---------- finalize ----------
__global__ __launch_bounds__(256) void fin_kernel(
    const float* __restrict__ nll, const int* __restrict__ alens,
    const int* __restrict__ step, const float* __restrict__ attn_losses,
    float* __restrict__ out)
{
    __shared__ float red[4];
    int tid = threadIdx.x;
    float s = 0.0f;
    for (int i = tid; i < B_ * T_TOK; i += 256) s += nll[i];
    #pragma unroll
    for (int off = 32; off > 0; off >>= 1) s += __shfl_xor(s, off);
    if ((tid & 63) == 0) red[tid >> 6] = s;
    __syncthreads();
    if (tid == 0) {
        float ce_sum = red[0] + red[1] + red[2] + red[3];
        int denom = 0;
        for (int b = 0; b < B_; b++) denom += min(alens[b], T_TOK);
        denom = max(denom, 1);
        float token = ce_sum / (float)denom;
        float a = 0.0f;
        for (int i = 0; i < NSEQ; i++) a += attn_losses[i];
        a *= (1.0f / NSEQ);
        if (step[0] <= 5000) a = 0.0f;
        out[0] = 1.5f * token + 10.0f * a;
        out[1] = a;
        out[2] = token;
    }
}

extern "C" void kernel_launch(void* const* d_in, const int* in_sizes, int n_in,
                              void* d_out, int out_size, void* d_ws, size_t ws_size,
                              hipStream_t stream)
{
    const float* logits  = (const float*)d_in[0];
    const float* attn    = (const float*)d_in[1];
    const int*   targets = (const int*)d_in[2];
    const int*   alens   = (const int*)d_in[3];
    const int*   slens   = (const int*)d_in[4];
    const int*   olens   = (const int*)d_in[5];
    const int*   step    = (const int*)d_in[6];
    float* out = (float*)d_out;
    float* ws  = (float*)d_ws;

    float* ws_attn = ws;            // [0..31]
    float* ws_nll  = ws + 64;       // [64 .. 64+8192)

    fused_kernel<<<dim3(NSEQ + B_ * T_TOK / 4), dim3(256), 0, stream>>>(
        logits, targets, alens, attn, slens, olens, ws_nll, ws_attn);
    fin_kernel<<<dim3(1), dim3(256), 0, stream>>>(ws_nll, alens, step, ws_attn, out);
}